// Round 4
// baseline (430.562 us; speedup 1.0000x reference)
//
#include <hip/hip_runtime.h>

// Problem: N=4, L=S=4096, H=8, D=64, fp32 in/out.
// out[n,l,h,:] = (Qf[l]·KV) / (Qf[l]·Ksum + eps),  Qf=elu+1(Q), Kf=elu+1(K)
// KV[d][e] = sum_s Kf[s][d]*V[s][e];  Ksum[d] = sum_s Kf[s][d]
#define NB   4
#define LQ   4096
#define SK   4096
#define NHD  8
#define DD   64
#define ROWSTRIDE 512
#define NHTOT 32
#define EPSF 1e-6f

// k1 tiling
#define CH     32                 // S-chunks per (n,h) -> 1024 blocks
#define SROWS  (SK / CH)          // 128 s-rows per block
#define TS     32                 // staged rows per iteration
#define NITER  (SROWS / TS)       // 4
#define KVSZ   (DD * DD)          // 4096
#define PART_STRIDE (KVSZ + DD)   // 4160

// k1 LDS carve (floats). Staging (stride 68) overlaid by reduce buffers.
#define SPAD     68
#define KS_OFF   0                // 32*68 = 2176
#define VS_OFF   2176             // 32*68 -> staging ends 4352
#define BUFA_OFF 0                // 64*64 = 4096 (after main loop)
#define BUFB_OFF 4096             // 64*64 -> 8192
#define KRED_OFF 8192             // 16*64 = 1024 (disjoint from staging+bufs)
#define SM_FLOATS 9216            // 36 KB -> 4 blocks/CU by LDS

__device__ __forceinline__ float fmap(float x) {
    return x > 0.f ? x + 1.f : __expf(x);   // elu(x)+1
}
__device__ __forceinline__ float4 fmap4(float4 v) {
    return make_float4(fmap(v.x), fmap(v.y), fmap(v.z), fmap(v.w));
}
__device__ __forceinline__ unsigned short f2bf(float f) {  // RNE bf16
    unsigned int u = __float_as_uint(f);
    return (unsigned short)((u + 0x7fffu + ((u >> 16) & 1u)) >> 16);
}

// ---------------------------------------------------------------------------
// k1: partial KV + Ksum per (nh, chunk). 256 thr = 4 waves split staged rows;
// 8x8 per-thread tile. part layout per block: flat lane-major chunks:
//   part[blk][c*256 + lane*4 + m] = acc[(4c+m)>>3][(4c+m)&7] of `lane`
//   part[blk][4096 + d]           = Ksum[d]
// (256,2): VGPR cap 256 — round-2's (256,4) 64-VGPR cap caused 137 MB spill.
// ---------------------------------------------------------------------------
__global__ __launch_bounds__(256, 2) void k1_kv(const float* __restrict__ Kin,
                                                const float* __restrict__ Vin,
                                                float* __restrict__ part) {
    __shared__ float sm[SM_FLOATS];
    const int blk   = blockIdx.x;
    const int nh    = blk >> 5;
    const int chunk = blk & 31;
    const int n = nh >> 3, h = nh & 7;
    const int t = threadIdx.x;
    const int w = t >> 6, lane = t & 63;
    const int d0 = (lane & 7) * 8;      // KV rows (d)
    const int e0 = (lane >> 3) * 8;     // KV cols (e)
    const int r = t >> 4;               // staging row 0..15 (and +16)
    const int c = (t & 15) * 4;         // staging col

    const size_t gbase = ((size_t)n * SK + (size_t)chunk * SROWS) * ROWSTRIDE
                         + (size_t)h * DD + c;
    const float* Kb = Kin + gbase;
    const float* Vb = Vin + gbase;

    float acc[8][8] = {};
    float ksl[4] = {0.f, 0.f, 0.f, 0.f};

    // prefetch tile 0
    float4 ka = *(const float4*)(Kb + (size_t)r * ROWSTRIDE);
    float4 kb = *(const float4*)(Kb + (size_t)(r + 16) * ROWSTRIDE);
    float4 va = *(const float4*)(Vb + (size_t)r * ROWSTRIDE);
    float4 vb = *(const float4*)(Vb + (size_t)(r + 16) * ROWSTRIDE);

    for (int it = 0; it < NITER; ++it) {
        float4 kfa = fmap4(ka), kfb = fmap4(kb);
        ksl[0] += kfa.x + kfb.x; ksl[1] += kfa.y + kfb.y;
        ksl[2] += kfa.z + kfb.z; ksl[3] += kfa.w + kfb.w;
        __syncthreads();                       // prev compute done reading LDS
        *(float4*)&sm[KS_OFF + r * SPAD + c]        = kfa;
        *(float4*)&sm[KS_OFF + (r + 16) * SPAD + c] = kfb;
        *(float4*)&sm[VS_OFF + r * SPAD + c]        = va;
        *(float4*)&sm[VS_OFF + (r + 16) * SPAD + c] = vb;
        __syncthreads();                       // stores visible
        if (it + 1 < NITER) {                  // prefetch next (hidden by compute)
            const size_t o = (size_t)(it + 1) * TS * ROWSTRIDE;
            ka = *(const float4*)(Kb + o + (size_t)r * ROWSTRIDE);
            kb = *(const float4*)(Kb + o + (size_t)(r + 16) * ROWSTRIDE);
            va = *(const float4*)(Vb + o + (size_t)r * ROWSTRIDE);
            vb = *(const float4*)(Vb + o + (size_t)(r + 16) * ROWSTRIDE);
        }
        const int sbase = w * 8;               // this wave's 8 s-rows
#pragma unroll
        for (int s = 0; s < 8; ++s) {
            const float* kr = &sm[KS_OFF + (sbase + s) * SPAD + d0];
            const float* vr = &sm[VS_OFF + (sbase + s) * SPAD + e0];
            float4 kA = *(const float4*)kr, kB = *(const float4*)(kr + 4);
            float4 vA = *(const float4*)vr, vB = *(const float4*)(vr + 4);
            float kk[8] = {kA.x, kA.y, kA.z, kA.w, kB.x, kB.y, kB.z, kB.w};
            float vv[8] = {vA.x, vA.y, vA.z, vA.w, vB.x, vB.y, vB.z, vB.w};
#pragma unroll
            for (int i = 0; i < 8; ++i)
#pragma unroll
                for (int j = 0; j < 8; ++j)
                    acc[i][j] += kk[i] * vv[j];
        }
    }

    // Ksum partials -> KRED (disjoint region; no barrier needed before write)
    *(float4*)&sm[KRED_OFF + r * DD + c] = make_float4(ksl[0], ksl[1], ksl[2], ksl[3]);
    __syncthreads();                                           // B1
    float ksumF = 0.f;
    if (w == 0) {
#pragma unroll
        for (int rr = 0; rr < 16; ++rr) ksumF += sm[KRED_OFF + rr * DD + lane];
    }
    // cross-wave KV reduce. Lane-major float4 chunks, XOR-rotated slot:
    // chunk c of lane -> sm[BUF + lane*64 + ((c+lane)&15)*4]  (canonical b128)
    if (w == 2) {
#pragma unroll
        for (int cc = 0; cc < 16; ++cc) {
            const int i = cc >> 1, j = (cc & 1) * 4;
            *(float4*)&sm[BUFA_OFF + lane * 64 + (((cc + lane) & 15) << 2)] =
                make_float4(acc[i][j], acc[i][j + 1], acc[i][j + 2], acc[i][j + 3]);
        }
    }
    if (w == 3) {
#pragma unroll
        for (int cc = 0; cc < 16; ++cc) {
            const int i = cc >> 1, j = (cc & 1) * 4;
            *(float4*)&sm[BUFB_OFF + lane * 64 + (((cc + lane) & 15) << 2)] =
                make_float4(acc[i][j], acc[i][j + 1], acc[i][j + 2], acc[i][j + 3]);
        }
    }
    __syncthreads();                                           // B2
    if (w == 0) {
#pragma unroll
        for (int cc = 0; cc < 16; ++cc) {
            const int i = cc >> 1, j = (cc & 1) * 4;
            float4 u = *(float4*)&sm[BUFA_OFF + lane * 64 + (((cc + lane) & 15) << 2)];
            acc[i][j] += u.x; acc[i][j+1] += u.y; acc[i][j+2] += u.z; acc[i][j+3] += u.w;
        }
    }
    if (w == 1) {
#pragma unroll
        for (int cc = 0; cc < 16; ++cc) {
            const int i = cc >> 1, j = (cc & 1) * 4;
            float4 u = *(float4*)&sm[BUFB_OFF + lane * 64 + (((cc + lane) & 15) << 2)];
            acc[i][j] += u.x; acc[i][j+1] += u.y; acc[i][j+2] += u.z; acc[i][j+3] += u.w;
        }
    }
    __syncthreads();                                           // B3
    if (w == 1) {
#pragma unroll
        for (int cc = 0; cc < 16; ++cc) {
            const int i = cc >> 1, j = (cc & 1) * 4;
            *(float4*)&sm[BUFA_OFF + lane * 64 + (((cc + lane) & 15) << 2)] =
                make_float4(acc[i][j], acc[i][j + 1], acc[i][j + 2], acc[i][j + 3]);
        }
    }
    __syncthreads();                                           // B4
    if (w == 0) {
        float* pb = part + ((size_t)nh * CH + chunk) * PART_STRIDE;
#pragma unroll
        for (int cc = 0; cc < 16; ++cc) {
            const int i = cc >> 1, j = (cc & 1) * 4;
            float4 u = *(float4*)&sm[BUFA_OFF + lane * 64 + (((cc + lane) & 15) << 2)];
            // coalesced: fixed cc -> lanes cover 1 KB contiguous
            *(float4*)(pb + (cc << 8) + (lane << 2)) =
                make_float4(acc[i][j] + u.x, acc[i][j + 1] + u.y,
                            acc[i][j + 2] + u.z, acc[i][j + 3] + u.w);
        }
        pb[KVSZ + lane] = ksumF;    // Ksum[d=lane]
    }
}

// ---------------------------------------------------------------------------
// k2: sum CH partials -> fin[nh][4160], float4-vectorized elementwise sum
// ---------------------------------------------------------------------------
#define K2_N (NHTOT * PART_STRIDE / 4)   // 33280 float4s
__global__ __launch_bounds__(256) void k2_reduce(const float* __restrict__ part,
                                                 float* __restrict__ fin) {
    const int idx = blockIdx.x * 256 + threadIdx.x;
    if (idx >= K2_N) return;
    const int nh = idx / (PART_STRIDE / 4);
    const int j  = (idx - nh * (PART_STRIDE / 4)) * 4;
    const float* p = part + (size_t)nh * CH * PART_STRIDE + j;
    float4 s = make_float4(0.f, 0.f, 0.f, 0.f);
#pragma unroll
    for (int cx = 0; cx < CH; ++cx) {
        float4 u = *(const float4*)(p + (size_t)cx * PART_STRIDE);
        s.x += u.x; s.y += u.y; s.z += u.z; s.w += u.w;
    }
    *(float4*)(fin + (size_t)nh * PART_STRIDE + j) = s;
}

// ---------------------------------------------------------------------------
// k3: out = (Qf·KV) / (Qf·Ksum + eps). 128 thr (2 waves), LT=128 l-rows,
// 8x8 per-thread tile, Q staged bf16 (QSTR=68 -> 34.1 KB total, 4 blk/CU).
// Explicit 2-stage register pipeline over dch4 steps: load batch it+1
// (8 q-b64 + 8 kv-b128 + 1 ks-b128), then 288 FMAs on batch it -> one
// lgkmcnt wait per ~576 VALU cycles (round-3: interleaved load-use at
// VGPR=104 left waves 70% stalled, VALUBusy 29%).
// ---------------------------------------------------------------------------
#define LT3  128
#define QSTR 68   // ushort row stride: 136 B, 8B-aligned, conflict-free b64
__global__ __launch_bounds__(128, 2) void k3_out(const float* __restrict__ Qin,
                                                 const float* __restrict__ fin,
                                                 float* __restrict__ out) {
    __shared__ unsigned short Qs[LT3 * QSTR];   // 17.4 KB
    __shared__ float KVs[DD * DD];              // 16.4 KB
    __shared__ float Ksm[DD];
    const int blk = blockIdx.x;
    const int nh  = blk >> 5;
    const int lc  = blk & 31;
    const int n = nh >> 3, h = nh & 7;
    const int t = threadIdx.x;
    const int w = t >> 6, lane = t & 63;

    // load final KV (de-swizzle: f = cc*256 + l*4 + m -> d,e) + Ksum
    const float* fb = fin + (size_t)nh * PART_STRIDE;
    for (int base = t * 4; base < KVSZ; base += 512) {
        float4 v = *(const float4*)(fb + base);
        const int cc = base >> 8;
        const int l  = (base & 255) >> 2;
        const float vals[4] = {v.x, v.y, v.z, v.w};
#pragma unroll
        for (int m = 0; m < 4; ++m) {
            const int k = (cc << 2) + m;
            const int d = ((l & 7) << 3) + (k >> 3);
            const int e = ((l >> 3) << 3) + (k & 7);
            KVs[d * DD + e] = vals[m];
        }
    }
    if (t < DD) Ksm[t] = fb[KVSZ + t];

    // stage Q (feature-mapped, bf16)
    const int r = t >> 4, c = (t & 15) * 4;
    const float* Qb = Qin + ((size_t)n * LQ + (size_t)lc * LT3) * ROWSTRIDE
                      + (size_t)h * DD + c;
    for (int rr = r; rr < LT3; rr += 8) {
        float4 q = *(const float4*)(Qb + (size_t)rr * ROWSTRIDE);
        float4 qf = fmap4(q);
        unsigned int w0 = (unsigned int)f2bf(qf.x) | ((unsigned int)f2bf(qf.y) << 16);
        unsigned int w1 = (unsigned int)f2bf(qf.z) | ((unsigned int)f2bf(qf.w) << 16);
        *(uint2*)&Qs[rr * QSTR + c] = make_uint2(w0, w1);
    }
    __syncthreads();

    const int e0 = (lane >> 3) * 8;
    const int rbase = w * 64 + (lane & 7);     // rows rbase + 8i

    // pipeline registers
    uint2  qb[2][8];
    float4 kvb[2][8];
    float4 ksb[2];
    float acc[8][8] = {};
    float z[8] = {};

#define LOADB(buf, dch)                                                        \
    {                                                                          \
        _Pragma("unroll")                                                      \
        for (int i = 0; i < 8; ++i)                                            \
            qb[buf][i] = *(const uint2*)&Qs[(rbase + 8 * i) * QSTR + (dch)];   \
        _Pragma("unroll")                                                      \
        for (int dd = 0; dd < 4; ++dd) {                                       \
            kvb[buf][2 * dd]     = *(const float4*)&KVs[((dch) + dd) * DD + e0];     \
            kvb[buf][2 * dd + 1] = *(const float4*)&KVs[((dch) + dd) * DD + e0 + 4]; \
        }                                                                      \
        ksb[buf] = *(const float4*)&Ksm[(dch)];                                \
    }

    LOADB(0, 0);
#pragma unroll
    for (int it = 0; it < 16; ++it) {
        const int cur = it & 1, nxt = cur ^ 1;
        if (it < 15) LOADB(nxt, (it + 1) * 4);
        const float4 ks4 = ksb[cur];
        const float4 a0 = kvb[cur][0], b0 = kvb[cur][1];
        const float4 a1 = kvb[cur][2], b1 = kvb[cur][3];
        const float4 a2 = kvb[cur][4], b2 = kvb[cur][5];
        const float4 a3 = kvb[cur][6], b3 = kvb[cur][7];
#pragma unroll
        for (int i = 0; i < 8; ++i) {
            const uint2 qw = qb[cur][i];
            const float q0 = __uint_as_float(qw.x << 16);
            const float q1 = __uint_as_float(qw.x & 0xffff0000u);
            const float q2 = __uint_as_float(qw.y << 16);
            const float q3 = __uint_as_float(qw.y & 0xffff0000u);
            z[i] += q0 * ks4.x + q1 * ks4.y + q2 * ks4.z + q3 * ks4.w;
            acc[i][0] += q0 * a0.x; acc[i][1] += q0 * a0.y;
            acc[i][2] += q0 * a0.z; acc[i][3] += q0 * a0.w;
            acc[i][4] += q0 * b0.x; acc[i][5] += q0 * b0.y;
            acc[i][6] += q0 * b0.z; acc[i][7] += q0 * b0.w;
            acc[i][0] += q1 * a1.x; acc[i][1] += q1 * a1.y;
            acc[i][2] += q1 * a1.z; acc[i][3] += q1 * a1.w;
            acc[i][4] += q1 * b1.x; acc[i][5] += q1 * b1.y;
            acc[i][6] += q1 * b1.z; acc[i][7] += q1 * b1.w;
            acc[i][0] += q2 * a2.x; acc[i][1] += q2 * a2.y;
            acc[i][2] += q2 * a2.z; acc[i][3] += q2 * a2.w;
            acc[i][4] += q2 * b2.x; acc[i][5] += q2 * b2.y;
            acc[i][6] += q2 * b2.z; acc[i][7] += q2 * b2.w;
            acc[i][0] += q3 * a3.x; acc[i][1] += q3 * a3.y;
            acc[i][2] += q3 * a3.z; acc[i][3] += q3 * a3.w;
            acc[i][4] += q3 * b3.x; acc[i][5] += q3 * b3.y;
            acc[i][6] += q3 * b3.z; acc[i][7] += q3 * b3.w;
        }
    }
#undef LOADB

    float* ob = out + ((size_t)n * LQ + (size_t)lc * LT3) * ROWSTRIDE
                + (size_t)h * DD;
#pragma unroll
    for (int i = 0; i < 8; ++i) {
        float zi = 1.f / (z[i] + EPSF);
        const size_t row = (size_t)(rbase + 8 * i) * ROWSTRIDE;
        *(float4*)(ob + row + e0) =
            make_float4(acc[i][0] * zi, acc[i][1] * zi, acc[i][2] * zi, acc[i][3] * zi);
        *(float4*)(ob + row + e0 + 4) =
            make_float4(acc[i][4] * zi, acc[i][5] * zi, acc[i][6] * zi, acc[i][7] * zi);
    }
}

// ---------------------------------------------------------------------------
extern "C" void kernel_launch(void* const* d_in, const int* in_sizes, int n_in,
                              void* d_out, int out_size, void* d_ws, size_t ws_size,
                              hipStream_t stream) {
    const float* Q = (const float*)d_in[0];
    const float* K = (const float*)d_in[1];
    const float* V = (const float*)d_in[2];
    float* out = (float*)d_out;

    float* ws   = (float*)d_ws;
    float* part = ws;                                        // 32*32*4160 floats (~17 MB)
    float* fin  = ws + (size_t)NHTOT * CH * PART_STRIDE;     // 32*4160 floats

    k1_kv<<<NHTOT * CH, 256, 0, stream>>>(K, V, part);
    k2_reduce<<<(K2_N + 255) / 256, 256, 0, stream>>>(part, fin);
    k3_out<<<NHTOT * (LQ / LT3), 128, 0, stream>>>(Q, fin, out);
}